// Round 6
// baseline (253.137 us; speedup 1.0000x reference)
//
#include <hip/hip_runtime.h>
#include <cstdint>

// BinConv2dEval: y = conv3x3(x,W) + bias; out = (sign*y >= 0) ? 1 : 0
// x: [32][128][64][64] fp32 in {0,1};  W: [256][128][3][3] fp32 in {-1,0,1}
// bias: [256] integer-valued fp32; sign: [256] in {-1,+1}; out fp32 NCHW.
//
// Strategy: all-integer implicit GEMM with i8 MFMA (16x16x64).
//  ws: xt = i8 NHWC zero-padded [32][66][66][128], chunk-swizzled (17.8 MB)
//      wq = i8 fragment-major [tap(9)][co64(4)][half(2)][c(4)][lane(64)x16B]
// R3: XOR-swizzle on xt chunks (LDS conflicts -> 0, verified).
// R5: fragment-major coalesced W loads, barrier-free K-loop.
// R6: 64co x 128m wave tiles (acc 32 v4i) — W global traffic is 72 KB per
//     wave tile regardless of tile size, so doubling outputs/wave halves
//     W bytes (590->295 MB). R4/R5 both plateaued at ~56 us because W
//     VMEM traffic (L1 15 us + L2 17 us per-CU-equivalent) stacked on
//     stores (21 us) dominated. Block = 128co x 256m (4 output rows),
//     X stage 6 rows = 49.5 KB, ~2 blocks/CU (VGPR-bound at 2 waves/SIMD).

#define NIMG 32
#define CIN  128
#define HH   64
#define WW   64
#define COUT 256
#define PH   66                       // padded spatial
#define XT_ROWSTRIDE (PH * CIN)       // 8448 bytes per padded row
#define XT_NSTRIDE   (PH * PH * CIN)  // 557568 bytes per image
#define XT_BYTES     ((size_t)NIMG * XT_NSTRIDE)
#define WP_TAPSTRIDE (COUT * CIN)     // 32768
#define WP_BYTES     ((size_t)9 * WP_TAPSTRIDE)

typedef int v4i __attribute__((ext_vector_type(4)));

// -------------------------------------------------------------------------
// Prepass: x fp32 NCHW -> i8 NHWC (chunk-swizzled), zero-padded borders.
// Swizzle: 16-B chunk c of pixel px lands at position c ^ (px & 7).
__global__ __launch_bounds__(256) void xt_prepass(const float* __restrict__ x,
                                                  int8_t* __restrict__ xt) {
    const int py = blockIdx.x;   // 0..65
    const int n  = blockIdx.y;   // 0..31
    const int t  = threadIdx.x;
    int8_t* rowbase = xt + (size_t)(n * PH + py) * XT_ROWSTRIDE;

    if (py == 0 || py == PH - 1) {          // pure pad row: zeros
        int4 z = {0, 0, 0, 0};
        for (int j = t; j < XT_ROWSTRIDE / 16; j += 256)
            ((int4*)rowbase)[j] = z;
        return;
    }

    __shared__ __align__(16) int8_t Ls[64 * 144];  // [x][ci], +16B row pad
    const int y  = py - 1;
    const int xq = t & 15;                  // float4 index along x
    const float4* xf = (const float4*)x;
#pragma unroll
    for (int j = 0; j < 8; ++j) {
        const int ci = (t >> 4) + j * 16;   // 0..127
        float4 v = xf[((size_t)(n * CIN + ci) * HH + y) * 16 + xq];
        const int xv = xq * 4;
        Ls[(xv + 0) * 144 + ci] = (int8_t)v.x;
        Ls[(xv + 1) * 144 + ci] = (int8_t)v.y;
        Ls[(xv + 2) * 144 + ci] = (int8_t)v.z;
        Ls[(xv + 3) * 144 + ci] = (int8_t)v.w;
    }
    __syncthreads();
    const int4 z = {0, 0, 0, 0};
    for (int j = t; j < XT_ROWSTRIDE / 16; j += 256) {   // 528 int4 chunks
        const int px  = j >> 3;             // 0..65
        const int c   = j & 7;              // source chunk within pixel
        int4 val;
        if (px == 0 || px == PH - 1) val = z;
        else                         val = *(const int4*)&Ls[(px - 1) * 144 + c * 16];
        *(int4*)(rowbase + (size_t)px * CIN + ((c ^ (px & 7)) << 4)) = val;
    }
}

// -------------------------------------------------------------------------
// Weight prepack: OIHW fp32 -> i8 fragment-major wq.
// dst = tap*32768 + cot*8192 + half*4096 + c*1024 + (quad*16+row)*16 + b
__global__ __launch_bounds__(256) void w_prepack(const float* __restrict__ w,
                                                 int8_t* __restrict__ wq) {
    const int idx = blockIdx.x * 256 + threadIdx.x;   // 0..294911
    if (idx >= (int)WP_BYTES) return;
    const int tap = idx >> 15;          // /32768
    const int rem = idx & 32767;
    const int co  = rem >> 7;
    const int ci  = rem & 127;
    const int half = ci >> 6, quad = (ci >> 4) & 3, b = ci & 15;
    const int cot = co >> 6, c = (co >> 4) & 3, row = co & 15;
    wq[tap * 32768 + cot * 8192 + half * 4096 + c * 1024
       + (quad * 16 + row) * 16 + b] =
        (int8_t)w[(size_t)(co * CIN + ci) * 9 + tap];
}

// -------------------------------------------------------------------------
// async global->LDS, 16B/lane. LDS dest = m0 (wave-uniform) + lane*16.
__device__ __forceinline__ void glds16(const void* g, uint32_t lds_off) {
    asm volatile("s_mov_b32 m0, %0\n"
                 "global_load_lds_dwordx4 %1, off"
                 :: "s"(lds_off), "v"(g) : "memory");
}

// -------------------------------------------------------------------------
// Main GEMM: D[co][m] = sum_taps W_tap[co][ci] * X_tap[ci][m]
// block: 128co x 256m (4 output rows x 64 cols), 4 waves, each 64co x 128m.
// X: 6 padded xt rows staged ONCE (49.5 KB + pad, swizzled, conflict-free).
// W: fragment-major coalesced global loads, 8 x 1KB per wave per tap.
// ZERO barriers after the initial X stage.
__global__ __launch_bounds__(256, 2) void binconv_gemm(
    const int8_t* __restrict__ xt, const int8_t* __restrict__ wq,
    const float* __restrict__ bias, const float* __restrict__ sign,
    float* __restrict__ out) {

    __shared__ __align__(16) int8_t Xraw[50 * 1024];  // 6*8448=50688, pad->51200

    const int t    = threadIdx.x;
    const int wid  = t >> 6;
    const int lane = t & 63;
    const int bx   = blockIdx.x;            // 512: n(32) x ystrip(16)
    const int co0  = blockIdx.y * 128;      // 0 / 128
    const int n    = bx >> 4;
    const int y0   = (bx & 15) << 2;        // 4 output rows per block

    // ---- stage 6 padded rows (50688 B) verbatim, once (50 x 1KB chunks;
    //      last chunk reads 512 B past the strip — always in-bounds of ws) ----
    const int8_t* xbase = xt + (size_t)n * XT_NSTRIDE + (size_t)y0 * XT_ROWSTRIDE;
    {
        const int8_t* gsrc = xbase + lane * 16;
        const uint32_t lds0 = (uint32_t)(uintptr_t)Xraw;
        for (int j = wid; j < 50; j += 4)
            glds16(gsrc + j * 1024,
                   __builtin_amdgcn_readfirstlane(lds0 + j * 1024));
        asm volatile("s_waitcnt vmcnt(0)" ::: "memory");
        __syncthreads();
    }

    const int row    = lane & 15;           // A: co-row   B: m-col
    const int quad   = lane >> 4;           // k quad (16 bytes)
    const int co_off = (wid >> 1) * 64;
    const int yw     = (wid & 1) * 2;       // wave's first output row in strip

    const int8_t* Xw  = Xraw + yw * XT_ROWSTRIDE;
    const int8_t* wqb = wq + ((co0 + co_off) >> 6) * 8192 + lane * 16;

    v4i acc[4][8] = {};                     // [co-subtile][m-subtile]

#pragma unroll
    for (int tap = 0; tap < 9; ++tap) {
        const int ky = tap / 3, kx = tap % 3;
        const int8_t* wqt = wqb + tap * 32768;
        const int8_t* xl  = Xw + ky * XT_ROWSTRIDE;
        const int pxr = row + kx;           // pixel for m=0; (px&7)=(pxr&7)

        v4i af[2][4];                       // all 8 A-fragments of this tap
#pragma unroll
        for (int h = 0; h < 2; ++h)
#pragma unroll
            for (int c = 0; c < 4; ++c)
                af[h][c] = *(const v4i*)(wqt + h * 4096 + c * 1024);

#pragma unroll
        for (int h = 0; h < 2; ++h) {
            const int swX = ((h * 4 + quad) ^ (pxr & 7)) << 4;
            v4i bf[8];
#pragma unroll
            for (int m = 0; m < 8; ++m)     // m>>2: output row, m&3: col/16
                bf[m] = *(const v4i*)(xl + (m >> 2) * XT_ROWSTRIDE
                                      + (pxr + (m & 3) * 16) * CIN + swX);
#pragma unroll
            for (int c = 0; c < 4; ++c)
#pragma unroll
                for (int m = 0; m < 8; ++m)
                    acc[c][m] = __builtin_amdgcn_mfma_i32_16x16x64_i8(
                        af[h][c], bf[m], acc[c][m], 0, 0, 0);
        }
    }

    // Epilogue. D 16x16 layout: col = lane&15 (m), row = quad*4 + reg (co).
    const float* bco = bias + co0 + co_off;
    const float* sco = sign + co0 + co_off;
    float* outb = out + ((size_t)n * COUT + co0 + co_off) * (HH * WW)
                + (y0 + yw) * WW;
#pragma unroll
    for (int c = 0; c < 4; ++c) {
#pragma unroll
        for (int r = 0; r < 4; ++r) {
            const int col_co = c * 16 + quad * 4 + r;
            const float bv = bco[col_co];
            const float sv = sco[col_co];
            float* orow = outb + (size_t)col_co * (HH * WW);
#pragma unroll
            for (int m = 0; m < 8; ++m) {
                const float yv = (float)acc[c][m][r] + bv;   // exact ints
                const bool on = (sv > 0.0f) ? (yv >= 0.0f) : (yv <= 0.0f);
                orow[(m >> 2) * WW + (m & 3) * 16 + row] = on ? 1.0f : 0.0f;
            }
        }
    }
}

// -------------------------------------------------------------------------
// Fallback (only if ws too small): naive direct conv, one thread per output.
__global__ __launch_bounds__(256) void naive_conv(
    const float* __restrict__ x, const float* __restrict__ w,
    const float* __restrict__ bias, const float* __restrict__ sign,
    float* __restrict__ out) {
    const int idx = blockIdx.x * 256 + threadIdx.x;
    const int xc = idx & 63, y = (idx >> 6) & 63, co = (idx >> 12) & 255,
              n = idx >> 20;
    float s = 0.f;
    for (int ci = 0; ci < CIN; ++ci)
        for (int ky = 0; ky < 3; ++ky) {
            const int iy = y + ky - 1;
            if (iy < 0 || iy >= HH) continue;
            for (int kx = 0; kx < 3; ++kx) {
                const int ix = xc + kx - 1;
                if (ix < 0 || ix >= WW) continue;
                s += x[((size_t)(n * CIN + ci) * HH + iy) * WW + ix] *
                     w[((size_t)(co * CIN + ci) * 3 + ky) * 3 + kx];
            }
        }
    const float yv = s + bias[co];
    out[idx] = ((sign[co] > 0.f) ? (yv >= 0.f) : (yv <= 0.f)) ? 1.0f : 0.0f;
}

// -------------------------------------------------------------------------
extern "C" void kernel_launch(void* const* d_in, const int* in_sizes, int n_in,
                              void* d_out, int out_size, void* d_ws, size_t ws_size,
                              hipStream_t stream) {
    const float* x    = (const float*)d_in[0];
    const float* w    = (const float*)d_in[1];
    const float* bias = (const float*)d_in[2];
    const float* sign = (const float*)d_in[3];
    float* out = (float*)d_out;

    const size_t need = XT_BYTES + WP_BYTES;   // ~18.1 MiB
    if (ws_size < need) {
        naive_conv<<<dim3((NIMG * COUT * HH * WW) / 256), 256, 0, stream>>>(
            x, w, bias, sign, out);
        return;
    }
    int8_t* xt = (int8_t*)d_ws;
    int8_t* wq = (int8_t*)d_ws + XT_BYTES;

    xt_prepass<<<dim3(PH, NIMG), 256, 0, stream>>>(x, xt);
    w_prepack<<<dim3((int)(WP_BYTES + 255) / 256), 256, 0, stream>>>(w, wq);
    binconv_gemm<<<dim3(NIMG * (HH / 4), COUT / 128), 256, 0, stream>>>(
        xt, wq, bias, sign, out);
}

// Round 8
// 217.484 us; speedup vs baseline: 1.1639x; 1.1639x over previous
//
#include <hip/hip_runtime.h>
#include <cstdint>

// BinConv2dEval: y = conv3x3(x,W) + bias; out = (sign*y >= 0) ? 1 : 0
// x: [32][128][64][64] fp32 in {0,1};  W: [256][128][3][3] fp32 in {-1,0,1}
// bias: [256] integer-valued fp32; sign: [256] in {-1,+1}; out fp32 NCHW.
//
// Strategy: all-integer implicit GEMM with i8 MFMA (16x16x64).
//  ws: xt = i8 NHWC zero-padded [32][66][66][128], chunk-swizzled (17.8 MB)
//      wq = i8 fragment-major [tap(9)][co64(4)][half(2)][c(4)][lane(64)x16B]
// R3: XOR-swizzle on xt chunks (LDS conflicts -> 0, verified).
// R5: fragment-major coalesced W loads, barrier-free K-loop (GEMM ~55 us).
// R6 FAILED: 2x m-tile spilled acc to scratch (VGPR cap 128, WRITE 275 MB).
// R7/R8: epilogue re-ordered through LDS so HBM writes are 256-B contiguous
//     bursts (D-layout direct stores were 64-B granules scattered across
//     128 co-planes at 16 KB stride -> ~3 TB/s write ceiling = the 55 us
//     plateau). NT stores via ext_vector float4 (R7's HIP float4 failed
//     to compile with __builtin_nontemporal_store).

#define NIMG 32
#define CIN  128
#define HH   64
#define WW   64
#define COUT 256
#define PH   66                       // padded spatial
#define XT_ROWSTRIDE (PH * CIN)       // 8448 bytes per padded row
#define XT_NSTRIDE   (PH * PH * CIN)  // 557568 bytes per image
#define XT_BYTES     ((size_t)NIMG * XT_NSTRIDE)
#define WP_TAPSTRIDE (COUT * CIN)     // 32768
#define WP_BYTES     ((size_t)9 * WP_TAPSTRIDE)

typedef int   v4i __attribute__((ext_vector_type(4)));
typedef float v4f __attribute__((ext_vector_type(4)));

// -------------------------------------------------------------------------
// Prepass: x fp32 NCHW -> i8 NHWC (chunk-swizzled), zero-padded borders.
// Swizzle: 16-B chunk c of pixel px lands at position c ^ (px & 7).
__global__ __launch_bounds__(256) void xt_prepass(const float* __restrict__ x,
                                                  int8_t* __restrict__ xt) {
    const int py = blockIdx.x;   // 0..65
    const int n  = blockIdx.y;   // 0..31
    const int t  = threadIdx.x;
    int8_t* rowbase = xt + (size_t)(n * PH + py) * XT_ROWSTRIDE;

    if (py == 0 || py == PH - 1) {          // pure pad row: zeros
        int4 z = {0, 0, 0, 0};
        for (int j = t; j < XT_ROWSTRIDE / 16; j += 256)
            ((int4*)rowbase)[j] = z;
        return;
    }

    __shared__ __align__(16) int8_t Ls[64 * 144];  // [x][ci], +16B row pad
    const int y  = py - 1;
    const int xq = t & 15;                  // float4 index along x
    const float4* xf = (const float4*)x;
#pragma unroll
    for (int j = 0; j < 8; ++j) {
        const int ci = (t >> 4) + j * 16;   // 0..127
        float4 v = xf[((size_t)(n * CIN + ci) * HH + y) * 16 + xq];
        const int xv = xq * 4;
        Ls[(xv + 0) * 144 + ci] = (int8_t)v.x;
        Ls[(xv + 1) * 144 + ci] = (int8_t)v.y;
        Ls[(xv + 2) * 144 + ci] = (int8_t)v.z;
        Ls[(xv + 3) * 144 + ci] = (int8_t)v.w;
    }
    __syncthreads();
    const int4 z = {0, 0, 0, 0};
    for (int j = t; j < XT_ROWSTRIDE / 16; j += 256) {   // 528 int4 chunks
        const int px  = j >> 3;             // 0..65
        const int c   = j & 7;              // source chunk within pixel
        int4 val;
        if (px == 0 || px == PH - 1) val = z;
        else                         val = *(const int4*)&Ls[(px - 1) * 144 + c * 16];
        *(int4*)(rowbase + (size_t)px * CIN + ((c ^ (px & 7)) << 4)) = val;
    }
}

// -------------------------------------------------------------------------
// Weight prepack: OIHW fp32 -> i8 fragment-major wq.
// dst = tap*32768 + cot*8192 + half*4096 + c*1024 + (quad*16+row)*16 + b
__global__ __launch_bounds__(256) void w_prepack(const float* __restrict__ w,
                                                 int8_t* __restrict__ wq) {
    const int idx = blockIdx.x * 256 + threadIdx.x;   // 0..294911
    if (idx >= (int)WP_BYTES) return;
    const int tap = idx >> 15;          // /32768
    const int rem = idx & 32767;
    const int co  = rem >> 7;
    const int ci  = rem & 127;
    const int half = ci >> 6, quad = (ci >> 4) & 3, b = ci & 15;
    const int cot = co >> 6, c = (co >> 4) & 3, row = co & 15;
    wq[tap * 32768 + cot * 8192 + half * 4096 + c * 1024
       + (quad * 16 + row) * 16 + b] =
        (int8_t)w[(size_t)(co * CIN + ci) * 9 + tap];
}

// -------------------------------------------------------------------------
// async global->LDS, 16B/lane. LDS dest = m0 (wave-uniform) + lane*16.
__device__ __forceinline__ void glds16(const void* g, uint32_t lds_off) {
    asm volatile("s_mov_b32 m0, %0\n"
                 "global_load_lds_dwordx4 %1, off"
                 :: "s"(lds_off), "v"(g) : "memory");
}

// -------------------------------------------------------------------------
// Main GEMM: D[co][m] = sum_taps W_tap[co][ci] * X_tap[ci][m]
// block: 128co x 128m (2 output rows x 64 cols), 4 waves, each 64co x 64m.
// X: 4 padded xt rows staged ONCE (33,792 B, swizzled, conflict-free).
// W: fragment-major coalesced global loads, 8 x 1KB per wave per tap.
// Epilogue: per-wave LDS transpose (u8) -> contiguous 256-B float4 NT
// stores (4 full output rows per instruction).
__global__ __launch_bounds__(256) void binconv_gemm(
    const int8_t* __restrict__ xt, const int8_t* __restrict__ wq,
    const float* __restrict__ bias, const float* __restrict__ sign,
    float* __restrict__ out) {

    __shared__ __align__(16) int8_t Xraw[4 * XT_ROWSTRIDE];  // 33,792 B

    const int t    = threadIdx.x;
    const int wid  = t >> 6;
    const int lane = t & 63;
    const int bx   = blockIdx.x;            // 1024 m-blocks
    const int co0  = blockIdx.y * 128;      // 0 / 128
    const int n    = bx >> 5;
    const int y0   = (bx & 31) << 1;        // 2 output rows per block

    // ---- stage 4 padded rows (33 KiB) verbatim, once ----
    const int8_t* xbase = xt + (size_t)n * XT_NSTRIDE + (size_t)y0 * XT_ROWSTRIDE;
    {
        const int8_t* gsrc = xbase + lane * 16;
        const uint32_t lds0 = (uint32_t)(uintptr_t)Xraw;
        for (int j = wid; j < 33; j += 4)    // 33 chunks of 1024 B
            glds16(gsrc + j * 1024,
                   __builtin_amdgcn_readfirstlane(lds0 + j * 1024));
        asm volatile("s_waitcnt vmcnt(0)" ::: "memory");
        __syncthreads();
    }

    const int row    = lane & 15;           // A: co-row   B: m-col
    const int quad   = lane >> 4;           // k quad (16 bytes)
    const int co_off = (wid >> 1) * 64;
    const int yw     = (wid & 1);           // wave's output row in {y0, y0+1}

    const int8_t* Xw  = Xraw + yw * XT_ROWSTRIDE;
    const int8_t* wqb = wq + ((co0 + co_off) >> 6) * 8192 + lane * 16;

    v4i acc[4][4] = {};                     // [co-subtile][m-subtile]

#pragma unroll
    for (int tap = 0; tap < 9; ++tap) {
        const int ky = tap / 3, kx = tap % 3;
        const int8_t* wqt = wqb + tap * 32768;
        const int8_t* xl  = Xw + ky * XT_ROWSTRIDE;
        const int pxr = row + kx;           // pixel for m=0; (px&7)=(pxr&7)

        v4i af[2][4];                       // all 8 A-fragments of this tap
#pragma unroll
        for (int h = 0; h < 2; ++h)
#pragma unroll
            for (int c = 0; c < 4; ++c)
                af[h][c] = *(const v4i*)(wqt + h * 4096 + c * 1024);

#pragma unroll
        for (int h = 0; h < 2; ++h) {
            const int swX = ((h * 4 + quad) ^ (pxr & 7)) << 4;
            v4i bf[4];
#pragma unroll
            for (int m = 0; m < 4; ++m)
                bf[m] = *(const v4i*)(xl + (pxr + m * 16) * CIN + swX);
#pragma unroll
            for (int c = 0; c < 4; ++c)
#pragma unroll
                for (int m = 0; m < 4; ++m)
                    acc[c][m] = __builtin_amdgcn_mfma_i32_16x16x64_i8(
                        af[h][c], bf[m], acc[c][m], 0, 0, 0);
        }
    }

    // ---- epilogue: threshold -> u8 in LDS (transpose) -> contiguous NT stores
    __syncthreads();                        // all waves done reading Xraw
    int8_t* Lep = Xraw + wid * 4096;        // wave-private [co64][m64] u8

    const float* bco = bias + co0 + co_off;
    const float* sco = sign + co0 + co_off;
#pragma unroll
    for (int c = 0; c < 4; ++c) {
#pragma unroll
        for (int r = 0; r < 4; ++r) {
            const int col_co = c * 16 + quad * 4 + r;
            const float bv = bco[col_co];
            const float sv = sco[col_co];
#pragma unroll
            for (int m = 0; m < 4; ++m) {
                const float yv = (float)acc[c][m][r] + bv;   // exact ints
                const bool on = (sv > 0.0f) ? (yv >= 0.0f) : (yv <= 0.0f);
                Lep[col_co * 64 + m * 16 + row] = (int8_t)on;
            }
        }
    }
    // intra-wave RAW on Lep: compiler inserts lgkmcnt wait; no barrier needed.
    float* outb = out + ((size_t)n * COUT + co0 + co_off) * (HH * WW)
                + (y0 + yw) * WW;           // this wave's output row
#pragma unroll
    for (int g = 0; g < 16; ++g) {
        const int p = g * 4 + quad;         // plane (co_local); 4 planes/instr
        const uint32_t u = *(const uint32_t*)&Lep[p * 64 + row * 4];
        v4f v;
        v.x = (float)( u        & 0xff);
        v.y = (float)((u >>  8) & 0xff);
        v.z = (float)((u >> 16) & 0xff);
        v.w = (float)((u >> 24) & 0xff);
        __builtin_nontemporal_store(v,
            (v4f*)(outb + (size_t)p * (HH * WW) + row * 4));
    }
}

// -------------------------------------------------------------------------
// Fallback (only if ws too small): naive direct conv, one thread per output.
__global__ __launch_bounds__(256) void naive_conv(
    const float* __restrict__ x, const float* __restrict__ w,
    const float* __restrict__ bias, const float* __restrict__ sign,
    float* __restrict__ out) {
    const int idx = blockIdx.x * 256 + threadIdx.x;
    const int xc = idx & 63, y = (idx >> 6) & 63, co = (idx >> 12) & 255,
              n = idx >> 20;
    float s = 0.f;
    for (int ci = 0; ci < CIN; ++ci)
        for (int ky = 0; ky < 3; ++ky) {
            const int iy = y + ky - 1;
            if (iy < 0 || iy >= HH) continue;
            for (int kx = 0; kx < 3; ++kx) {
                const int ix = xc + kx - 1;
                if (ix < 0 || ix >= WW) continue;
                s += x[((size_t)(n * CIN + ci) * HH + iy) * WW + ix] *
                     w[((size_t)(co * CIN + ci) * 3 + ky) * 3 + kx];
            }
        }
    const float yv = s + bias[co];
    out[idx] = ((sign[co] > 0.f) ? (yv >= 0.f) : (yv <= 0.f)) ? 1.0f : 0.0f;
}

// -------------------------------------------------------------------------
extern "C" void kernel_launch(void* const* d_in, const int* in_sizes, int n_in,
                              void* d_out, int out_size, void* d_ws, size_t ws_size,
                              hipStream_t stream) {
    const float* x    = (const float*)d_in[0];
    const float* w    = (const float*)d_in[1];
    const float* bias = (const float*)d_in[2];
    const float* sign = (const float*)d_in[3];
    float* out = (float*)d_out;

    const size_t need = XT_BYTES + WP_BYTES;   // ~18.1 MiB
    if (ws_size < need) {
        naive_conv<<<dim3((NIMG * COUT * HH * WW) / 256), 256, 0, stream>>>(
            x, w, bias, sign, out);
        return;
    }
    int8_t* xt = (int8_t*)d_ws;
    int8_t* wq = (int8_t*)d_ws + XT_BYTES;

    xt_prepass<<<dim3(PH, NIMG), 256, 0, stream>>>(x, xt);
    w_prepack<<<dim3((int)(WP_BYTES + 255) / 256), 256, 0, stream>>>(w, wq);
    binconv_gemm<<<dim3(NIMG * (HH / 2), COUT / 128), 256, 0, stream>>>(
        xt, wq, bias, sign, out);
}